// Round 10
// baseline (32.475 us; speedup 1.0000x reference)
//
#include <hip/hip_runtime.h>

#define LOG2E 1.4426950408889634f
#define C1 (10.0f * LOG2E)

// Single fused kernel. grid 2048 = (b:4, co:32, chunk:16 of 2 output rows).
// 256 threads = 4 waves; wave w owns ci in [4w, 4w+4); 1 pixel/lane.
// Math per term: cn = 1/(1+E1*T1); u = fma(Zk,x,A) - B*cn; out -= W2/(1+2^u)
//   with T1=2^(C1*Ec), Zk=2*LOG2E*k, A=Zk*Ec, B=0.2*A, W2=2*Ps*coef.
// BOTH reciprocals batched 3-wide (one v_rcp per nb-group per phase).
// LDS = 17408(sX) + 6912(sP) + 1728(sW) + 16 = 26064 B -> 6 blocks/CU at (256,6).
__global__ __launch_bounds__(256, 6) void fused_kernel(
    const float* __restrict__ x, const float* __restrict__ kk,
    const float* __restrict__ Ec, const float* __restrict__ Ps,
    const float* __restrict__ bias, const float* __restrict__ coef,
    const float* __restrict__ out_bias, float* __restrict__ out) {
    __shared__ float2 sX[2176];   // [ci:16][r:4][c:34] = (x, E1=2^(C1 x)), pad->(0,1)
    __shared__ float4 sP[432];    // [ci:16][j:9][nb:3] = {T1, Zk, A, B}
    __shared__ float  sW[432];    // W2
    __shared__ float  wK0[4];

    const int bid = blockIdx.x, tid = threadIdx.x;
    const int chunk = bid & 15;
    const int co    = (bid >> 4) & 31;
    const int b     = bid >> 9;

    // ---- stage x / E1 slab (rows chunk*2-1 .. chunk*2+2, cols -1..32) ----
    for (int t = tid; t < 2176; t += 256) {
        int ci  = t / 136;
        int rem = t - ci * 136;
        int r   = rem / 34;
        int c   = rem - r * 34;
        int row = chunk * 2 + r - 1;
        int col = c - 1;
        float xv = 0.f;
        if ((unsigned)row < 32u && (unsigned)col < 32u)
            xv = x[((b * 16 + ci) << 10) + (row << 5) + col];
        sX[t] = make_float2(xv, __builtin_amdgcn_exp2f(C1 * xv));
    }

    // ---- derive this co's params; K0 partial ----
    float kpart = 0.f;
    for (int t = tid; t < 432; t += 256) {
        int ci = t / 27;
        int r2 = t - ci * 27;
        int j  = r2 / 3;
        int nb = r2 - j * 3;
        int i  = co * 432 + ci * 27 + nb * 9 + j;   // input layout [ci][nb][j]
        float e  = Ec[i];
        float zk = 2.0f * LOG2E * kk[i];
        float a  = zk * e;
        float ps = Ps[i], cf = coef[i];
        sP[t] = make_float4(__builtin_amdgcn_exp2f(C1 * e), zk, a, 0.2f * a);
        sW[t] = 2.0f * ps * cf;
        kpart += cf * (ps + bias[i]);
    }
    #pragma unroll
    for (int off = 32; off >= 1; off >>= 1) kpart += __shfl_down(kpart, off, 64);
    if ((tid & 63) == 0) wK0[tid >> 6] = kpart;
    __syncthreads();

    // ---- main compute ----
    const int px = tid & 63;
    const int w  = px & 31;
    const int hr = px >> 5;                 // 0..1
    const int cb = (tid >> 6) << 2;

    float a0 = 0.f, a1 = 0.f, a2 = 0.f;
    #pragma unroll
    for (int i = 0; i < 4; ++i) {
        const float2* xw = &sX[(cb + i) * 136 + hr * 34 + w];
        float2 X[9];
        #pragma unroll
        for (int j = 0; j < 9; ++j)
            X[j] = xw[(j / 3) * 34 + (j % 3)];
        const float4* pc = &sP[(cb + i) * 27];
        const float*  wc = &sW[(cb + i) * 27];
        #pragma unroll
        for (int j = 0; j < 9; ++j) {
            const float xv = X[j].x, E1 = X[j].y;
            const float4 P0 = pc[j * 3 + 0];
            const float4 P1 = pc[j * 3 + 1];
            const float4 P2 = pc[j * 3 + 2];
            const float w0 = wc[j * 3 + 0];
            const float w1 = wc[j * 3 + 1];
            const float w2v = wc[j * 3 + 2];
            // phase 1: cn_i = 1/d_i, one rcp for the 3 nb
            float d0 = fminf(__builtin_fmaf(E1, P0.x, 1.f), 0x1p40f);
            float d1 = fminf(__builtin_fmaf(E1, P1.x, 1.f), 0x1p40f);
            float d2 = fminf(__builtin_fmaf(E1, P2.x, 1.f), 0x1p40f);
            float q01 = d0 * d1, q12 = d1 * d2, q02 = d0 * d2;
            float rp = __builtin_amdgcn_rcpf(q01 * d2);
            float t0 = __builtin_fmaf(P0.y, xv, P0.z);
            float t1 = __builtin_fmaf(P1.y, xv, P1.z);
            float t2 = __builtin_fmaf(P2.y, xv, P2.z);
            float m0 = P0.w * q12, m1 = P1.w * q02, m2 = P2.w * q01;
            float u0 = __builtin_fmaf(-m0, rp, t0);
            float u1 = __builtin_fmaf(-m1, rp, t1);
            float u2 = __builtin_fmaf(-m2, rp, t2);
            // phase 2: r_i = 1/(1+2^u_i), one rcp for the 3 nb
            float e0 = __builtin_amdgcn_exp2f(u0);
            float e1 = __builtin_amdgcn_exp2f(u1);
            float e2 = __builtin_amdgcn_exp2f(u2);
            float f0 = fminf(1.f + e0, 0x1p42f);
            float f1 = fminf(1.f + e1, 0x1p42f);
            float f2 = fminf(1.f + e2, 0x1p42f);
            float s01 = f0 * f1, s12 = f1 * f2, s02 = f0 * f2;
            float rq = __builtin_amdgcn_rcpf(s01 * f2);
            float n0 = w0 * s12, n1 = w1 * s02, n2 = w2v * s01;
            a0 = __builtin_fmaf(-n0, rq, a0);
            a1 = __builtin_fmaf(-n1, rq, a1);
            a2 = __builtin_fmaf(-n2, rq, a2);
        }
    }

    // ---- cross-wave reduce (alias sX as scratch; all sX reads are done) ----
    __syncthreads();
    float* red = (float*)sX;
    red[tid] = a0 + a1 + a2;
    __syncthreads();
    if (tid < 64) {
        float r = red[tid] + red[tid + 64] + red[tid + 128] + red[tid + 192];
        float k0 = wK0[0] + wK0[1] + wK0[2] + wK0[3] + out_bias[co];
        int o = ((b * 32 + co) << 10) + (chunk << 6) + tid;
        out[o] = r + k0;
    }
}

extern "C" void kernel_launch(void* const* d_in, const int* in_sizes, int n_in,
                              void* d_out, int out_size, void* d_ws, size_t ws_size,
                              hipStream_t stream) {
    const float* x        = (const float*)d_in[0];
    const float* k        = (const float*)d_in[1];
    const float* Ec       = (const float*)d_in[2];
    const float* Ps       = (const float*)d_in[3];
    const float* bias     = (const float*)d_in[4];
    const float* coef     = (const float*)d_in[5];
    const float* out_bias = (const float*)d_in[6];
    float* out = (float*)d_out;

    fused_kernel<<<2048, 256, 0, stream>>>(x, k, Ec, Ps, bias, coef, out_bias, out);
}

// Round 11
// 32.292 us; speedup vs baseline: 1.0057x; 1.0057x over previous
//
#include <hip/hip_runtime.h>

#define LOG2E 1.4426950408889634f
#define C1 (10.0f * LOG2E)

// Fast reciprocal: bit-trick seed + 2 Newton-Raphson steps.
// 5 full-rate VALU ops vs one quarter/eighth-rate v_rcp_f32.
// Valid for x in (2^-125, 2^125); rel err <= ~1.4e-6, one-sided (underestimates).
__device__ __forceinline__ float fastrcp(float x) {
    float y = __uint_as_float(0x7EF311C3u - __float_as_uint(x));
    y = y * __builtin_fmaf(-x, y, 2.0f);
    y = y * __builtin_fmaf(-x, y, 2.0f);
    return y;
}

// Single fused kernel. grid 2048 = (b:4, co:32, chunk:16 of 2 output rows).
// 256 threads = 4 waves; wave w owns ci in [4w, 4w+4); 1 pixel/lane.
// Identical structure to the 28.57us R7 kernel; ONLY the two v_rcp_f32 are
// replaced by fastrcp (the discriminating experiment for the trans-issue model).
__global__ __launch_bounds__(256, 6) void fused_kernel(
    const float* __restrict__ x, const float* __restrict__ kk,
    const float* __restrict__ Ec, const float* __restrict__ Ps,
    const float* __restrict__ bias, const float* __restrict__ coef,
    const float* __restrict__ out_bias, float* __restrict__ out) {
    __shared__ float2 sX[2176];   // [ci:16][r:4][c:34] = (x, E1=2^(C1 x)), pad->(0,1)
    __shared__ float4 sP[432];    // [ci:16][j:9][nb:3] = {T1, Zk, A=Zk*Ec, W2}
    __shared__ float  red[256];
    __shared__ float  wK0[4];

    const int bid = blockIdx.x, tid = threadIdx.x;
    const int chunk = bid & 15;
    const int co    = (bid >> 4) & 31;
    const int b     = bid >> 9;

    // ---- stage x / E1 slab (rows chunk*2-1 .. chunk*2+2, cols -1..32) ----
    for (int t = tid; t < 2176; t += 256) {
        int ci  = t / 136;
        int rem = t - ci * 136;
        int r   = rem / 34;
        int c   = rem - r * 34;
        int row = chunk * 2 + r - 1;
        int col = c - 1;
        float xv = 0.f;
        if ((unsigned)row < 32u && (unsigned)col < 32u)
            xv = x[((b * 16 + ci) << 10) + (row << 5) + col];
        sX[t] = make_float2(xv, __builtin_amdgcn_exp2f(C1 * xv));
    }

    // ---- derive this co's params; K0 partial ----
    float kpart = 0.f;
    for (int t = tid; t < 432; t += 256) {
        int ci = t / 27;
        int r2 = t - ci * 27;
        int j  = r2 / 3;
        int nb = r2 - j * 3;
        int i  = co * 432 + ci * 27 + nb * 9 + j;   // input layout [ci][nb][j]
        float e  = Ec[i];
        float zk = 2.0f * LOG2E * kk[i];
        float ps = Ps[i], cf = coef[i];
        sP[t] = make_float4(__builtin_amdgcn_exp2f(C1 * e), zk, zk * e, 2.0f * ps * cf);
        kpart += cf * (ps + bias[i]);
    }
    #pragma unroll
    for (int off = 32; off >= 1; off >>= 1) kpart += __shfl_down(kpart, off, 64);
    if ((tid & 63) == 0) wK0[tid >> 6] = kpart;
    __syncthreads();

    // ---- main compute ----
    const int px = tid & 63;
    const int w  = px & 31;
    const int hr = px >> 5;                 // 0..1
    const int cb = (tid >> 6) << 2;

    float a0 = 0.f, a1 = 0.f, a2 = 0.f;
    #pragma unroll
    for (int i = 0; i < 4; ++i) {
        const float2* xw = &sX[(cb + i) * 136 + hr * 34 + w];
        float2 X[9];
        #pragma unroll
        for (int j = 0; j < 9; ++j)
            X[j] = xw[(j / 3) * 34 + (j % 3)];
        const float4* pc = &sP[(cb + i) * 27];
        #pragma unroll
        for (int j = 0; j < 9; ++j) {
            const float xv = X[j].x, E1 = X[j].y;
            const float4 P0 = pc[j * 3 + 0];
            const float4 P1 = pc[j * 3 + 1];
            const float4 P2 = pc[j * 3 + 2];
            float cn0 = fastrcp(__builtin_fmaf(E1, P0.x, 1.f));
            float cn1 = fastrcp(__builtin_fmaf(E1, P1.x, 1.f));
            float cn2 = fastrcp(__builtin_fmaf(E1, P2.x, 1.f));
            float t0 = __builtin_fmaf(P0.y, xv, P0.z);
            float t1 = __builtin_fmaf(P1.y, xv, P1.z);
            float t2 = __builtin_fmaf(P2.y, xv, P2.z);
            float u0 = __builtin_fmaf(-0.2f * P0.z, cn0, t0);
            float u1 = __builtin_fmaf(-0.2f * P1.z, cn1, t1);
            float u2 = __builtin_fmaf(-0.2f * P2.z, cn2, t2);
            float e0 = __builtin_amdgcn_exp2f(u0);
            float e1 = __builtin_amdgcn_exp2f(u1);
            float e2 = __builtin_amdgcn_exp2f(u2);
            float r0 = fastrcp(1.f + e0);
            float r1 = fastrcp(1.f + e1);
            float r2 = fastrcp(1.f + e2);
            a0 = __builtin_fmaf(-P0.w, r0, a0);
            a1 = __builtin_fmaf(-P1.w, r1, a1);
            a2 = __builtin_fmaf(-P2.w, r2, a2);
        }
    }
    red[tid] = a0 + a1 + a2;
    __syncthreads();
    if (tid < 64) {
        float r = red[tid] + red[tid + 64] + red[tid + 128] + red[tid + 192];
        float k0 = wK0[0] + wK0[1] + wK0[2] + wK0[3] + out_bias[co];
        int o = ((b * 32 + co) << 10) + (chunk << 6) + tid;
        out[o] = r + k0;
    }
}

extern "C" void kernel_launch(void* const* d_in, const int* in_sizes, int n_in,
                              void* d_out, int out_size, void* d_ws, size_t ws_size,
                              hipStream_t stream) {
    const float* x        = (const float*)d_in[0];
    const float* k        = (const float*)d_in[1];
    const float* Ec       = (const float*)d_in[2];
    const float* Ps       = (const float*)d_in[3];
    const float* bias     = (const float*)d_in[4];
    const float* coef     = (const float*)d_in[5];
    const float* out_bias = (const float*)d_in[6];
    float* out = (float*)d_out;

    fused_kernel<<<2048, 256, 0, stream>>>(x, k, Ec, Ps, bias, coef, out_bias, out);
}

// Round 12
// 27.814 us; speedup vs baseline: 1.1676x; 1.1610x over previous
//
#include <hip/hip_runtime.h>

#define LOG2E 1.4426950408889634f
#define C1 (10.0f * LOG2E)

// Single fused kernel. grid 2048 = (b:4, co:32, chunk:16 of 2 output rows).
// 256 threads = 4 waves; wave w owns ci in [4w, 4w+4); 1 pixel/lane.
// (256,8) + 17.4 KB LDS -> 8 blocks/CU resident: grid 2048 = ONE generation, no tail.
// Math per term: cn = 1/(1+E1*T1); u = fma(Zk,x,A) - B*cn; out -= W2/(1+2^u)
//   T1=2^(C1*Ec), Zk=2*LOG2E*k, A=Zk*Ec, B=0.2*A, W2=2*Ps*coef, E1=2^(C1*x) (in-loop).
__global__ __launch_bounds__(256, 8) void fused_kernel(
    const float* __restrict__ x, const float* __restrict__ kk,
    const float* __restrict__ Ec, const float* __restrict__ Ps,
    const float* __restrict__ bias, const float* __restrict__ coef,
    const float* __restrict__ out_bias, float* __restrict__ out) {
    __shared__ float  sX[2176];   // [ci:16][r:4][c:34] = x, pad->0  (8704 B)
    __shared__ float4 sP[432];    // [ci:16][j:9][nb:3] = {T1, Zk, A, B} (6912 B)
    __shared__ float  sW[432];    // W2 (1728 B)
    __shared__ float  wK0[4];

    const int bid = blockIdx.x, tid = threadIdx.x;
    const int chunk = bid & 15;
    const int co    = (bid >> 4) & 31;
    const int b     = bid >> 9;

    // ---- stage x slab (rows chunk*2-1 .. chunk*2+2, cols -1..32) ----
    for (int t = tid; t < 2176; t += 256) {
        int ci  = t / 136;
        int rem = t - ci * 136;
        int r   = rem / 34;
        int c   = rem - r * 34;
        int row = chunk * 2 + r - 1;
        int col = c - 1;
        float xv = 0.f;
        if ((unsigned)row < 32u && (unsigned)col < 32u)
            xv = x[((b * 16 + ci) << 10) + (row << 5) + col];
        sX[t] = xv;
    }

    // ---- derive this co's params; K0 partial ----
    float kpart = 0.f;
    for (int t = tid; t < 432; t += 256) {
        int ci = t / 27;
        int r2 = t - ci * 27;
        int j  = r2 / 3;
        int nb = r2 - j * 3;
        int i  = co * 432 + ci * 27 + nb * 9 + j;   // input layout [ci][nb][j]
        float e  = Ec[i];
        float zk = 2.0f * LOG2E * kk[i];
        float a  = zk * e;
        float ps = Ps[i], cf = coef[i];
        sP[t] = make_float4(__builtin_amdgcn_exp2f(C1 * e), zk, a, 0.2f * a);
        sW[t] = 2.0f * ps * cf;
        kpart += cf * (ps + bias[i]);
    }
    #pragma unroll
    for (int off = 32; off >= 1; off >>= 1) kpart += __shfl_down(kpart, off, 64);
    if ((tid & 63) == 0) wK0[tid >> 6] = kpart;
    __syncthreads();

    // ---- main compute ----
    const int px = tid & 63;
    const int w  = px & 31;
    const int hr = px >> 5;                 // 0..1
    const int cb = (tid >> 6) << 2;

    float a0 = 0.f, a1 = 0.f, a2 = 0.f;
    #pragma unroll
    for (int i = 0; i < 4; ++i) {
        const float* xw = &sX[(cb + i) * 136 + hr * 34 + w];
        float X[9], E[9];
        #pragma unroll
        for (int j = 0; j < 9; ++j)
            X[j] = xw[(j / 3) * 34 + (j % 3)];
        #pragma unroll
        for (int j = 0; j < 9; ++j)
            E[j] = __builtin_amdgcn_exp2f(C1 * X[j]);
        const float4* pc = &sP[(cb + i) * 27];
        const float*  wc = &sW[(cb + i) * 27];
        #pragma unroll
        for (int j = 0; j < 9; ++j) {
            const float xv = X[j], E1 = E[j];
            const float4 P0 = pc[j * 3 + 0];
            const float4 P1 = pc[j * 3 + 1];
            const float4 P2 = pc[j * 3 + 2];
            const float w0 = wc[j * 3 + 0];
            const float w1 = wc[j * 3 + 1];
            const float w2v = wc[j * 3 + 2];
            float cn0 = __builtin_amdgcn_rcpf(__builtin_fmaf(E1, P0.x, 1.f));
            float cn1 = __builtin_amdgcn_rcpf(__builtin_fmaf(E1, P1.x, 1.f));
            float cn2 = __builtin_amdgcn_rcpf(__builtin_fmaf(E1, P2.x, 1.f));
            float t0 = __builtin_fmaf(P0.y, xv, P0.z);
            float t1 = __builtin_fmaf(P1.y, xv, P1.z);
            float t2 = __builtin_fmaf(P2.y, xv, P2.z);
            float u0 = __builtin_fmaf(-P0.w, cn0, t0);
            float u1 = __builtin_fmaf(-P1.w, cn1, t1);
            float u2 = __builtin_fmaf(-P2.w, cn2, t2);
            float e0 = __builtin_amdgcn_exp2f(u0);
            float e1 = __builtin_amdgcn_exp2f(u1);
            float e2 = __builtin_amdgcn_exp2f(u2);
            float r0 = __builtin_amdgcn_rcpf(1.f + e0);
            float r1 = __builtin_amdgcn_rcpf(1.f + e1);
            float r2 = __builtin_amdgcn_rcpf(1.f + e2);
            a0 = __builtin_fmaf(-w0, r0, a0);
            a1 = __builtin_fmaf(-w1, r1, a1);
            a2 = __builtin_fmaf(-w2v, r2, a2);
        }
    }

    // ---- cross-wave reduce (alias sX; all sX reads done) ----
    __syncthreads();
    float* red = sX;
    red[tid] = a0 + a1 + a2;
    __syncthreads();
    if (tid < 64) {
        float r = red[tid] + red[tid + 64] + red[tid + 128] + red[tid + 192];
        float k0 = wK0[0] + wK0[1] + wK0[2] + wK0[3] + out_bias[co];
        int o = ((b * 32 + co) << 10) + (chunk << 6) + tid;
        out[o] = r + k0;
    }
}

extern "C" void kernel_launch(void* const* d_in, const int* in_sizes, int n_in,
                              void* d_out, int out_size, void* d_ws, size_t ws_size,
                              hipStream_t stream) {
    const float* x        = (const float*)d_in[0];
    const float* k        = (const float*)d_in[1];
    const float* Ec       = (const float*)d_in[2];
    const float* Ps       = (const float*)d_in[3];
    const float* bias     = (const float*)d_in[4];
    const float* coef     = (const float*)d_in[5];
    const float* out_bias = (const float*)d_in[6];
    float* out = (float*)d_out;

    fused_kernel<<<2048, 256, 0, stream>>>(x, k, Ec, Ps, bias, coef, out_bias, out);
}